// Round 1
// baseline (1384.523 us; speedup 1.0000x reference)
//
#include <hip/hip_runtime.h>

#define NB   16
#define NPC  4096
#define MPC  1024
#define KNB  64
#define FIN  64
#define CAP  448   // candidate capacity per centroid (mean ~137, +26 sigma)

typedef unsigned short u16;
typedef unsigned int   u32;
typedef unsigned long long u64;
typedef __attribute__((ext_vector_type(8))) short short8;
typedef __attribute__((ext_vector_type(4))) float f32x4;

__device__ __forceinline__ u16 f2bf(float f) {
  u32 u = __float_as_uint(f);
  u = u + 0x7fffu + ((u >> 16) & 1u);
  return (u16)(u >> 16);
}
__device__ __forceinline__ float bf2f(u16 b) {
  return __uint_as_float(((u32)b) << 16);
}

// ---------------------------------------------------------------- FPS
// One block per cloud. Bit-exact vs numpy: no FMA contraction, (x2+y2)+z2
// order, argmax first-index tie-break via packed (dist_bits<<32)|~idx.
__global__ __launch_bounds__(1024)
void fps_kernel(const float* __restrict__ pos, int* __restrict__ idx_out,
                float* __restrict__ pos_out, float* __restrict__ batch_out) {
  const int b = blockIdx.x;
  const int t = threadIdx.x;
  const float* P = pos + (size_t)b * NPC * 3;
  __shared__ float sx[NPC], sy[NPC], sz[NPC];
  __shared__ u64 swave[2][16];
  for (int i = t; i < NPC; i += 1024) {
    sx[i] = P[3*i+0]; sy[i] = P[3*i+1]; sz[i] = P[3*i+2];
  }
  batch_out[b*MPC + t] = (float)b;
  __syncthreads();
  float px[4], py[4], pz[4], mind[4];
#pragma unroll
  for (int r = 0; r < 4; ++r) {
    int i = t + (r << 10);
    px[r] = sx[i]; py[r] = sy[i]; pz[r] = sz[i];
    mind[r] = __builtin_inff();
  }
  int last = 0;
  if (t == 0) {
    idx_out[b*MPC] = 0;
    pos_out[(size_t)b*MPC*3 + 0] = sx[0];
    pos_out[(size_t)b*MPC*3 + 1] = sy[0];
    pos_out[(size_t)b*MPC*3 + 2] = sz[0];
  }
  for (int m = 1; m < MPC; ++m) {
    float cx = sx[last], cy = sy[last], cz = sz[last];
    u64 best = 0;
#pragma unroll
    for (int r = 0; r < 4; ++r) {
      float dx = __fsub_rn(px[r], cx);
      float dy = __fsub_rn(py[r], cy);
      float dz = __fsub_rn(pz[r], cz);
      float d2 = __fadd_rn(__fadd_rn(__fmul_rn(dx,dx), __fmul_rn(dy,dy)), __fmul_rn(dz,dz));
      mind[r] = fminf(mind[r], d2);
      u64 key = ((u64)__float_as_uint(mind[r]) << 32) | (u32)(~(u32)(t + (r << 10)));
      best = key > best ? key : best;
    }
#pragma unroll
    for (int off = 1; off < 64; off <<= 1) {
      u64 o = __shfl_xor(best, off, 64);
      best = o > best ? o : best;
    }
    if ((t & 63) == 0) swave[m & 1][t >> 6] = best;
    __syncthreads();   // single barrier per step (parity double-buffer)
    u64 w = swave[m & 1][0];
#pragma unroll
    for (int q = 1; q < 16; ++q) {
      u64 o = swave[m & 1][q];
      w = o > w ? o : w;
    }
    last = (int)(~(u32)w);
    if (t == 0) {
      idx_out[b*MPC + m] = last;
      size_t po = ((size_t)b*MPC + m)*3;
      pos_out[po+0] = sx[last]; pos_out[po+1] = sy[last]; pos_out[po+2] = sz[last];
    }
  }
}

// ---------------------------------------------------------------- y = x @ W1[:64]  (f32 accum, bf16 store)
__global__ __launch_bounds__(256)
void y_kernel(const float* __restrict__ x, const float* __restrict__ w1,
              u16* __restrict__ y) {
  __shared__ float xs[64][68];
  __shared__ float ws[64][68];
  const int t = threadIdx.x;
  const size_t row0 = (size_t)blockIdx.x * 64;
#pragma unroll
  for (int k = 0; k < 4; ++k) {
    int l = t + 256*k;               // 0..1023 float4 index
    int r = l >> 4, c4 = l & 15;
    *(float4*)&xs[r][c4*4] = *(const float4*)&x[(row0 + r)*64 + c4*4];
    *(float4*)&ws[r][c4*4] = *(const float4*)&w1[r*64 + c4*4];
  }
  __syncthreads();
  const int r = t >> 2, c0 = (t & 3) << 4;
  float acc[16];
#pragma unroll
  for (int i = 0; i < 16; ++i) acc[i] = 0.f;
  for (int k = 0; k < 64; ++k) {
    float a = xs[r][k];
#pragma unroll
    for (int j = 0; j < 4; ++j) {
      float4 wv = *(const float4*)&ws[k][c0 + 4*j];
      acc[4*j+0] += a * wv.x; acc[4*j+1] += a * wv.y;
      acc[4*j+2] += a * wv.z; acc[4*j+3] += a * wv.w;
    }
  }
  u32 u[8];
#pragma unroll
  for (int i = 0; i < 8; ++i)
    u[i] = (u32)f2bf(acc[2*i]) | ((u32)f2bf(acc[2*i+1]) << 16);
  u16* dst = y + ((row0 + r)*64 + c0);
  ((uint4*)dst)[0] = make_uint4(u[0],u[1],u[2],u[3]);
  ((uint4*)dst)[1] = make_uint4(u[4],u[5],u[6],u[7]);
}

// ---------------------------------------------------------------- W2 -> bf16 transposed [128][64]
__global__ __launch_bounds__(256)
void w2t_kernel(const float* __restrict__ w2, u16* __restrict__ w2t) {
  int t = blockIdx.x*256 + threadIdx.x;
  if (t < 64*128) {
    int k = t >> 7, c = t & 127;
    w2t[c*64 + k] = f2bf(w2[t]);
  }
}

// ---------------------------------------------------------------- radius + top-64 neighbors
// Replicates lax.top_k(-d2,64) stability via key=(d2_bits, idx) ranking.
__global__ __launch_bounds__(256)
void nbr_kernel(const float* __restrict__ pos, const int* __restrict__ idx,
                int* __restrict__ nbr, int* __restrict__ nvalid) {
  const int bid = blockIdx.x;
  const int sw = (bid & 7) * 512 + (bid >> 3);   // bijective XCD swizzle (4096 = 8*512)
  const int cloud = sw >> 8;
  const int mbase = (sw & 255) << 2;
  __shared__ float sx[NPC], sy[NPC], sz[NPC];
  __shared__ u64 cand[4][CAP];
  const float* P = pos + (size_t)cloud * NPC * 3;
  const int t = threadIdx.x;
  for (int i = t; i < NPC; i += 256) { sx[i]=P[3*i]; sy[i]=P[3*i+1]; sz[i]=P[3*i+2]; }
  __syncthreads();
  const int wv = t >> 6, lane = t & 63;
  const int m = mbase + wv;
  const int g = cloud * MPC + m;
  const int ci = idx[g];
  const float cx = sx[ci], cy = sy[ci], cz = sz[ci];
  const float R2 = 0.04000000059604644775f;      // (float)(0.2*0.2)
  const u64 ltmask = (lane == 0) ? 0ull : (~0ull >> (64 - lane));
  int base = 0;
  for (int i = 0; i < NPC/64; ++i) {
    int j = (i << 6) + lane;
    float dx = __fsub_rn(cx, sx[j]);
    float dy = __fsub_rn(cy, sy[j]);
    float dz = __fsub_rn(cz, sz[j]);
    float d2 = __fadd_rn(__fadd_rn(__fmul_rn(dx,dx), __fmul_rn(dy,dy)), __fmul_rn(dz,dz));
    bool in = d2 <= R2;
    u64 mk = __ballot(in);
    if (in) {
      int slot = base + (int)__popcll(mk & ltmask);
      if (slot < CAP)
        cand[wv][slot] = ((u64)__float_as_uint(d2) << 32) | (u32)j;
    }
    base += (int)__popcll(mk);
  }
  int cnt = base < CAP ? base : CAP;
  u64 mykey[7];
  int myrank[7];
#pragma unroll
  for (int u = 0; u < 7; ++u) {
    int s = lane + (u << 6);
    mykey[u] = (s < cnt) ? cand[wv][s] : ~0ull;
    myrank[u] = 0;
  }
  for (int jj = 0; jj < cnt; ++jj) {
    u64 kj = cand[wv][jj];
#pragma unroll
    for (int u = 0; u < 7; ++u) myrank[u] += (kj < mykey[u]) ? 1 : 0;
  }
#pragma unroll
  for (int u = 0; u < 7; ++u) {
    int s = lane + (u << 6);
    if (s < cnt && myrank[u] < KNB)
      nbr[(size_t)g*KNB + myrank[u]] = cloud*NPC + (int)(mykey[u] & 0xffffffffull);
  }
  if (lane == 0) nvalid[g] = cnt < KNB ? cnt : KNB;
}

// ---------------------------------------------------------------- PointNetConv (one block per centroid)
__global__ __launch_bounds__(256)
void conv_kernel(const float* __restrict__ pos, const int* __restrict__ idx,
                 const int* __restrict__ nbr, const int* __restrict__ nvalid,
                 const u16* __restrict__ y, const u16* __restrict__ w2t,
                 const float* __restrict__ w1, const float* __restrict__ b1,
                 const float* __restrict__ b2, float* __restrict__ out) {
  const int bid = blockIdx.x;
  const int g = (bid & 7) * 2048 + (bid >> 3);   // bijective XCD swizzle (16384 = 8*2048)
  const int cloud = g >> 10;
  __shared__ u16 YH[64][72];     // y rows, then relu'd H1 in-place (same-thread RMW)
  __shared__ u16 WT[128][72];    // W2^T bf16
  __shared__ float rel[64][3];
  __shared__ int nbs[64];
  __shared__ float w1p[192];
  __shared__ float b1s[64];
  const int t = threadIdx.x;
  const int nv = nvalid[g];
  if (t < 64) nbs[t] = (t < nv) ? nbr[(size_t)g*KNB + t] : -1;
  if (t < 192) w1p[t] = w1[64*64 + t];
  else         b1s[t - 192] = b1[t - 192];
  __syncthreads();
  if (t < 64) {
    int ci = cloud*NPC + idx[g];
    float cxx = pos[3*ci], cyy = pos[3*ci+1], czz = pos[3*ci+2];
    int j = nbs[t];
    float r0 = 0.f, r1 = 0.f, r2 = 0.f;
    if (t < nv && j >= 0) {
      r0 = pos[3*j]   - cxx;
      r1 = pos[3*j+1] - cyy;
      r2 = pos[3*j+2] - czz;
    }
    rel[t][0] = r0; rel[t][1] = r1; rel[t][2] = r2;
  }
  {
    int row = t >> 2, part = t & 3;
    int j = nbs[row];
    uint4 v0 = make_uint4(0,0,0,0), v1 = make_uint4(0,0,0,0);
    if (row < nv && j >= 0) {
      const uint4* src = (const uint4*)(y + (size_t)j*64);
      v0 = src[part*2]; v1 = src[part*2 + 1];
    }
    *(uint4*)&YH[row][part*16]     = v0;
    *(uint4*)&YH[row][part*16 + 8] = v1;
  }
#pragma unroll
  for (int k = 0; k < 4; ++k) {
    int l = t + 256*k;             // 1024 uint4 total
    int row = l >> 3, part = l & 7;
    *(uint4*)&WT[row][part*8] = ((const uint4*)w2t)[l];
  }
  __syncthreads();
  {
    int s = t >> 2, c0 = (t & 3) << 4;
    float rx = rel[s][0], ry = rel[s][1], rz = rel[s][2];
#pragma unroll
    for (int c = 0; c < 16; ++c) {
      int cc = c0 + c;
      float v = bf2f(YH[s][cc]) + rx*w1p[cc] + ry*w1p[64+cc] + rz*w1p[128+cc] + b1s[cc];
      v = fmaxf(v, 0.f);
      YH[s][cc] = f2bf(v);
    }
  }
  __syncthreads();
  const int wv = t >> 6, lane = t & 63;
  const int arow = lane & 15, agrp = lane >> 4;
  const int col0 = wv << 5;
  f32x4 acc[4][2];
#pragma unroll
  for (int mt = 0; mt < 4; ++mt)
#pragma unroll
    for (int nt = 0; nt < 2; ++nt) {
      f32x4 z = {0.f, 0.f, 0.f, 0.f};
      acc[mt][nt] = z;
    }
#pragma unroll
  for (int kk = 0; kk < 2; ++kk) {
    short8 a[4], bm[2];
#pragma unroll
    for (int mt = 0; mt < 4; ++mt)
      a[mt] = *(const short8*)&YH[mt*16 + arow][kk*32 + agrp*8];
#pragma unroll
    for (int nt = 0; nt < 2; ++nt)
      bm[nt] = *(const short8*)&WT[col0 + nt*16 + arow][kk*32 + agrp*8];
#pragma unroll
    for (int mt = 0; mt < 4; ++mt)
#pragma unroll
      for (int nt = 0; nt < 2; ++nt)
        acc[mt][nt] = __builtin_amdgcn_mfma_f32_16x16x32_bf16(a[mt], bm[nt], acc[mt][nt], 0, 0, 0);
  }
  float p0 = -__builtin_inff(), p1 = -__builtin_inff();
#pragma unroll
  for (int mt = 0; mt < 4; ++mt) {
#pragma unroll
    for (int r = 0; r < 4; ++r) {
      int slot = mt*16 + agrp*4 + r;
      if (slot < nv) {
        p0 = fmaxf(p0, acc[mt][0][r]);
        p1 = fmaxf(p1, acc[mt][1][r]);
      }
    }
  }
  p0 = fmaxf(p0, __shfl_xor(p0, 16, 64));
  p0 = fmaxf(p0, __shfl_xor(p0, 32, 64));
  p1 = fmaxf(p1, __shfl_xor(p1, 16, 64));
  p1 = fmaxf(p1, __shfl_xor(p1, 32, 64));
  if (lane < 16) {
    int c = col0 + lane;
    out[(size_t)g*128 + c]      = (nv > 0) ? p0 + b2[c]      : 0.f;
    out[(size_t)g*128 + c + 16] = (nv > 0) ? p1 + b2[c + 16] : 0.f;
  }
}

// ---------------------------------------------------------------- launch
extern "C" void kernel_launch(void* const* d_in, const int* in_sizes, int n_in,
                              void* d_out, int out_size, void* d_ws, size_t ws_size,
                              hipStream_t stream) {
  const float* x   = (const float*)d_in[0];
  const float* pos = (const float*)d_in[1];
  // d_in[2] (batch) unused: layout is known (repeat arange(16), 4096 each)
  const float* W1  = (const float*)d_in[3];
  const float* b1  = (const float*)d_in[4];
  const float* W2  = (const float*)d_in[5];
  const float* b2  = (const float*)d_in[6];

  float* out       = (float*)d_out;                    // [16384,128]
  float* pos_out   = out + (size_t)NB*MPC*128;         // [16384,3]
  float* batch_out = pos_out + (size_t)NB*MPC*3;       // [16384] (written as floats)

  char* ws = (char*)d_ws;
  int* idx    = (int*)(ws);                                    // 16384 * 4   = 64 KB
  int* nvalid = (int*)(ws + 65536);                            // 16384 * 4   = 64 KB
  int* nbr    = (int*)(ws + 131072);                           // 16384*64*4  = 4 MB
  u16* w2t    = (u16*)(ws + 131072 + 4194304);                 // 128*64*2    = 16 KB
  u16* y      = (u16*)(ws + 131072 + 4194304 + 16384);         // 65536*64*2  = 8 MB (16B aligned)

  fps_kernel <<<NB,    1024, 0, stream>>>(pos, idx, pos_out, batch_out);
  y_kernel   <<<1024,  256,  0, stream>>>(x, W1, y);
  w2t_kernel <<<32,    256,  0, stream>>>(W2, w2t);
  nbr_kernel <<<4096,  256,  0, stream>>>(pos, idx, nbr, nvalid);
  conv_kernel<<<16384, 256,  0, stream>>>(pos, idx, nbr, nvalid, y, w2t, W1, b1, b2, out);
}

// Round 3
// 899.072 us; speedup vs baseline: 1.5399x; 1.5399x over previous
//
#include <hip/hip_runtime.h>

#define NB   16
#define NPC  4096
#define MPC  1024
#define KNB  64
#define FIN  64
#define CAP  448   // candidate capacity per centroid (mean ~137, +26 sigma)

typedef unsigned short u16;
typedef unsigned int   u32;
typedef unsigned long long u64;
typedef __attribute__((ext_vector_type(8))) short short8;
typedef __attribute__((ext_vector_type(4))) float f32x4;

__device__ __forceinline__ u16 f2bf(float f) {
  u32 u = __float_as_uint(f);
  u = u + 0x7fffu + ((u >> 16) & 1u);
  return (u16)(u >> 16);
}
__device__ __forceinline__ float bf2f(u16 b) {
  return __uint_as_float(((u32)b) << 16);
}

// 64-lane wave reduce on the VALU pipe via DPP (v_mov_b32_dpp + v_max/min).
// __builtin_amdgcn_update_dpp lets the COMPILER insert the mandatory DPP
// read-after-VALU-write wait states (raw asm without s_nop faults/garbage).
// ctrl: 0x111/0x112/0x114/0x118 = row_shr:1/2/4/8; 0x142 = row_bcast:15
// (row_mask 0xa); 0x143 = row_bcast:31 (row_mask 0xc). bound_ctrl=false =>
// invalid/masked lanes keep `old` (= x), so max(x, dpp) is a no-op there.
// Result valid in lane 63.
__device__ __forceinline__ u32 wave_max_u32(u32 x) {
  u32 t;
  t = (u32)__builtin_amdgcn_update_dpp((int)x, (int)x, 0x111, 0xf, 0xf, false); x = x > t ? x : t;
  t = (u32)__builtin_amdgcn_update_dpp((int)x, (int)x, 0x112, 0xf, 0xf, false); x = x > t ? x : t;
  t = (u32)__builtin_amdgcn_update_dpp((int)x, (int)x, 0x114, 0xf, 0xf, false); x = x > t ? x : t;
  t = (u32)__builtin_amdgcn_update_dpp((int)x, (int)x, 0x118, 0xf, 0xf, false); x = x > t ? x : t;
  t = (u32)__builtin_amdgcn_update_dpp((int)x, (int)x, 0x142, 0xa, 0xf, false); x = x > t ? x : t;
  t = (u32)__builtin_amdgcn_update_dpp((int)x, (int)x, 0x143, 0xc, 0xf, false); x = x > t ? x : t;
  return x;
}
__device__ __forceinline__ u32 wave_min_u32(u32 x) {
  u32 t;
  t = (u32)__builtin_amdgcn_update_dpp((int)x, (int)x, 0x111, 0xf, 0xf, false); x = x < t ? x : t;
  t = (u32)__builtin_amdgcn_update_dpp((int)x, (int)x, 0x112, 0xf, 0xf, false); x = x < t ? x : t;
  t = (u32)__builtin_amdgcn_update_dpp((int)x, (int)x, 0x114, 0xf, 0xf, false); x = x < t ? x : t;
  t = (u32)__builtin_amdgcn_update_dpp((int)x, (int)x, 0x118, 0xf, 0xf, false); x = x < t ? x : t;
  t = (u32)__builtin_amdgcn_update_dpp((int)x, (int)x, 0x142, 0xa, 0xf, false); x = x < t ? x : t;
  t = (u32)__builtin_amdgcn_update_dpp((int)x, (int)x, 0x143, 0xc, 0xf, false); x = x < t ? x : t;
  return x;
}

// ---------------------------------------------------------------- FPS
// One block (512 thr = 8 waves) per cloud. Bit-exact vs numpy: no FMA
// contraction, (x2+y2)+z2 order, argmax first-index tie-break via
// (value-max, then index-min) two-phase reduce. dist >= 0 so u32 compare
// of float bits == float compare.
__global__ __launch_bounds__(512)
void fps_kernel(const float* __restrict__ pos, int* __restrict__ idx_out,
                float* __restrict__ pos_out, float* __restrict__ batch_out) {
  const int b = blockIdx.x;
  const int t = threadIdx.x;
  const float* P = pos + (size_t)b * NPC * 3;
  __shared__ float sx[NPC], sy[NPC], sz[NPC];
  __shared__ u64 swave[2][8];
  for (int i = t; i < NPC; i += 512) {
    sx[i] = P[3*i+0]; sy[i] = P[3*i+1]; sz[i] = P[3*i+2];
  }
  for (int i = t; i < MPC; i += 512) batch_out[b*MPC + i] = (float)b;
  __syncthreads();
  float px[8], py[8], pz[8], mind[8];
#pragma unroll
  for (int r = 0; r < 8; ++r) {
    int i = t + (r << 9);
    px[r] = sx[i]; py[r] = sy[i]; pz[r] = sz[i];
    mind[r] = __builtin_inff();
  }
  int last = 0;
  if (t == 0) {
    idx_out[b*MPC] = 0;
    pos_out[(size_t)b*MPC*3 + 0] = sx[0];
    pos_out[(size_t)b*MPC*3 + 1] = sy[0];
    pos_out[(size_t)b*MPC*3 + 2] = sz[0];
  }
  for (int m = 1; m < MPC; ++m) {
    float cx = sx[last], cy = sy[last], cz = sz[last];
    u32 vmax = 0;
#pragma unroll
    for (int r = 0; r < 8; ++r) {
      float dx = __fsub_rn(px[r], cx);
      float dy = __fsub_rn(py[r], cy);
      float dz = __fsub_rn(pz[r], cz);
      float d2 = __fadd_rn(__fadd_rn(__fmul_rn(dx,dx), __fmul_rn(dy,dy)), __fmul_rn(dz,dz));
      mind[r] = fminf(mind[r], d2);
      u32 bits = __float_as_uint(mind[r]);
      vmax = bits > vmax ? bits : vmax;
    }
    vmax = wave_max_u32(vmax);
    u32 V = (u32)__builtin_amdgcn_readlane((int)vmax, 63);
    u32 cand = 0xffffffffu;
#pragma unroll
    for (int r = 7; r >= 0; --r)
      cand = (__float_as_uint(mind[r]) == V) ? (u32)(t + (r << 9)) : cand;
    cand = wave_min_u32(cand);
    if ((t & 63) == 63) swave[m & 1][t >> 6] = ((u64)V << 32) | (u32)(~cand);
    __syncthreads();   // single barrier per step (parity double-buffer)
    u64 w = swave[m & 1][0];
#pragma unroll
    for (int q = 1; q < 8; ++q) {
      u64 o = swave[m & 1][q];
      w = o > w ? o : w;
    }
    last = (int)(~(u32)w);
    if (t == 0) {
      idx_out[b*MPC + m] = last;
      size_t po = ((size_t)b*MPC + m)*3;
      pos_out[po+0] = sx[last]; pos_out[po+1] = sy[last]; pos_out[po+2] = sz[last];
    }
  }
}

// ---------------------------------------------------------------- y = x @ W1[:64]  (f32 accum, bf16 store)
__global__ __launch_bounds__(256)
void y_kernel(const float* __restrict__ x, const float* __restrict__ w1,
              u16* __restrict__ y) {
  __shared__ float xs[64][68];
  __shared__ float ws[64][68];
  const int t = threadIdx.x;
  const size_t row0 = (size_t)blockIdx.x * 64;
#pragma unroll
  for (int k = 0; k < 4; ++k) {
    int l = t + 256*k;               // 0..1023 float4 index
    int r = l >> 4, c4 = l & 15;
    *(float4*)&xs[r][c4*4] = *(const float4*)&x[(row0 + r)*64 + c4*4];
    *(float4*)&ws[r][c4*4] = *(const float4*)&w1[r*64 + c4*4];
  }
  __syncthreads();
  const int r = t >> 2, c0 = (t & 3) << 4;
  float acc[16];
#pragma unroll
  for (int i = 0; i < 16; ++i) acc[i] = 0.f;
  for (int k = 0; k < 64; ++k) {
    float a = xs[r][k];
#pragma unroll
    for (int j = 0; j < 4; ++j) {
      float4 wv = *(const float4*)&ws[k][c0 + 4*j];
      acc[4*j+0] += a * wv.x; acc[4*j+1] += a * wv.y;
      acc[4*j+2] += a * wv.z; acc[4*j+3] += a * wv.w;
    }
  }
  u32 u[8];
#pragma unroll
  for (int i = 0; i < 8; ++i)
    u[i] = (u32)f2bf(acc[2*i]) | ((u32)f2bf(acc[2*i+1]) << 16);
  u16* dst = y + ((row0 + r)*64 + c0);
  ((uint4*)dst)[0] = make_uint4(u[0],u[1],u[2],u[3]);
  ((uint4*)dst)[1] = make_uint4(u[4],u[5],u[6],u[7]);
}

// ---------------------------------------------------------------- W2 -> bf16 transposed [128][64]
__global__ __launch_bounds__(256)
void w2t_kernel(const float* __restrict__ w2, u16* __restrict__ w2t) {
  int t = blockIdx.x*256 + threadIdx.x;
  if (t < 64*128) {
    int k = t >> 7, c = t & 127;
    w2t[c*64 + k] = f2bf(w2[t]);
  }
}

// ---------------------------------------------------------------- radius + top-64 neighbors
// Replicates lax.top_k(-d2,64) stability via key=(d2_bits, idx) ranking.
__global__ __launch_bounds__(256)
void nbr_kernel(const float* __restrict__ pos, const int* __restrict__ idx,
                int* __restrict__ nbr, int* __restrict__ nvalid) {
  const int bid = blockIdx.x;
  const int sw = (bid & 7) * 512 + (bid >> 3);   // bijective XCD swizzle (4096 = 8*512)
  const int cloud = sw >> 8;
  const int mbase = (sw & 255) << 2;
  __shared__ float sx[NPC], sy[NPC], sz[NPC];
  __shared__ u64 cand[4][CAP];
  const float* P = pos + (size_t)cloud * NPC * 3;
  const int t = threadIdx.x;
  for (int i = t; i < NPC; i += 256) { sx[i]=P[3*i]; sy[i]=P[3*i+1]; sz[i]=P[3*i+2]; }
  __syncthreads();
  const int wv = t >> 6, lane = t & 63;
  const int m = mbase + wv;
  const int g = cloud * MPC + m;
  const int ci = idx[g];
  const float cx = sx[ci], cy = sy[ci], cz = sz[ci];
  const float R2 = 0.04000000059604644775f;      // (float)(0.2*0.2)
  const u64 ltmask = (lane == 0) ? 0ull : (~0ull >> (64 - lane));
  int base = 0;
  for (int i = 0; i < NPC/64; ++i) {
    int j = (i << 6) + lane;
    float dx = __fsub_rn(cx, sx[j]);
    float dy = __fsub_rn(cy, sy[j]);
    float dz = __fsub_rn(cz, sz[j]);
    float d2 = __fadd_rn(__fadd_rn(__fmul_rn(dx,dx), __fmul_rn(dy,dy)), __fmul_rn(dz,dz));
    bool in = d2 <= R2;
    u64 mk = __ballot(in);
    if (in) {
      int slot = base + (int)__popcll(mk & ltmask);
      if (slot < CAP)
        cand[wv][slot] = ((u64)__float_as_uint(d2) << 32) | (u32)j;
    }
    base += (int)__popcll(mk);
  }
  int cnt = base < CAP ? base : CAP;
  u64 mykey[7];
  int myrank[7];
#pragma unroll
  for (int u = 0; u < 7; ++u) {
    int s = lane + (u << 6);
    mykey[u] = (s < cnt) ? cand[wv][s] : ~0ull;
    myrank[u] = 0;
  }
  for (int jj = 0; jj < cnt; ++jj) {
    u64 kj = cand[wv][jj];
#pragma unroll
    for (int u = 0; u < 7; ++u) myrank[u] += (kj < mykey[u]) ? 1 : 0;
  }
#pragma unroll
  for (int u = 0; u < 7; ++u) {
    int s = lane + (u << 6);
    if (s < cnt && myrank[u] < KNB)
      nbr[(size_t)g*KNB + myrank[u]] = cloud*NPC + (int)(mykey[u] & 0xffffffffull);
  }
  if (lane == 0) nvalid[g] = cnt < KNB ? cnt : KNB;
}

// ---------------------------------------------------------------- PointNetConv (one block per centroid)
__global__ __launch_bounds__(256)
void conv_kernel(const float* __restrict__ pos, const int* __restrict__ idx,
                 const int* __restrict__ nbr, const int* __restrict__ nvalid,
                 const u16* __restrict__ y, const u16* __restrict__ w2t,
                 const float* __restrict__ w1, const float* __restrict__ b1,
                 const float* __restrict__ b2, float* __restrict__ out) {
  const int bid = blockIdx.x;
  const int g = (bid & 7) * 2048 + (bid >> 3);   // bijective XCD swizzle (16384 = 8*2048)
  const int cloud = g >> 10;
  __shared__ u16 YH[64][72];     // y rows, then relu'd H1 in-place (same-thread RMW)
  __shared__ u16 WT[128][72];    // W2^T bf16
  __shared__ float rel[64][3];
  __shared__ int nbs[64];
  __shared__ float w1p[192];
  __shared__ float b1s[64];
  const int t = threadIdx.x;
  const int nv = nvalid[g];
  if (t < 64) nbs[t] = (t < nv) ? nbr[(size_t)g*KNB + t] : -1;
  if (t < 192) w1p[t] = w1[64*64 + t];
  else         b1s[t - 192] = b1[t - 192];
  __syncthreads();
  if (t < 64) {
    int ci = cloud*NPC + idx[g];
    float cxx = pos[3*ci], cyy = pos[3*ci+1], czz = pos[3*ci+2];
    int j = nbs[t];
    float r0 = 0.f, r1 = 0.f, r2 = 0.f;
    if (t < nv && j >= 0) {
      r0 = pos[3*j]   - cxx;
      r1 = pos[3*j+1] - cyy;
      r2 = pos[3*j+2] - czz;
    }
    rel[t][0] = r0; rel[t][1] = r1; rel[t][2] = r2;
  }
  {
    int row = t >> 2, part = t & 3;
    int j = nbs[row];
    uint4 v0 = make_uint4(0,0,0,0), v1 = make_uint4(0,0,0,0);
    if (row < nv && j >= 0) {
      const uint4* src = (const uint4*)(y + (size_t)j*64);
      v0 = src[part*2]; v1 = src[part*2 + 1];
    }
    *(uint4*)&YH[row][part*16]     = v0;
    *(uint4*)&YH[row][part*16 + 8] = v1;
  }
#pragma unroll
  for (int k = 0; k < 4; ++k) {
    int l = t + 256*k;             // 1024 uint4 total
    int row = l >> 3, part = l & 7;
    *(uint4*)&WT[row][part*8] = ((const uint4*)w2t)[l];
  }
  __syncthreads();
  {
    int s = t >> 2, c0 = (t & 3) << 4;
    float rx = rel[s][0], ry = rel[s][1], rz = rel[s][2];
#pragma unroll
    for (int c = 0; c < 16; ++c) {
      int cc = c0 + c;
      float v = bf2f(YH[s][cc]) + rx*w1p[cc] + ry*w1p[64+cc] + rz*w1p[128+cc] + b1s[cc];
      v = fmaxf(v, 0.f);
      YH[s][cc] = f2bf(v);
    }
  }
  __syncthreads();
  const int wv = t >> 6, lane = t & 63;
  const int arow = lane & 15, agrp = lane >> 4;
  const int col0 = wv << 5;
  f32x4 acc[4][2];
#pragma unroll
  for (int mt = 0; mt < 4; ++mt)
#pragma unroll
    for (int nt = 0; nt < 2; ++nt) {
      f32x4 z = {0.f, 0.f, 0.f, 0.f};
      acc[mt][nt] = z;
    }
#pragma unroll
  for (int kk = 0; kk < 2; ++kk) {
    short8 a[4], bm[2];
#pragma unroll
    for (int mt = 0; mt < 4; ++mt)
      a[mt] = *(const short8*)&YH[mt*16 + arow][kk*32 + agrp*8];
#pragma unroll
    for (int nt = 0; nt < 2; ++nt)
      bm[nt] = *(const short8*)&WT[col0 + nt*16 + arow][kk*32 + agrp*8];
#pragma unroll
    for (int mt = 0; mt < 4; ++mt)
#pragma unroll
      for (int nt = 0; nt < 2; ++nt)
        acc[mt][nt] = __builtin_amdgcn_mfma_f32_16x16x32_bf16(a[mt], bm[nt], acc[mt][nt], 0, 0, 0);
  }
  float p0 = -__builtin_inff(), p1 = -__builtin_inff();
#pragma unroll
  for (int mt = 0; mt < 4; ++mt) {
#pragma unroll
    for (int r = 0; r < 4; ++r) {
      int slot = mt*16 + agrp*4 + r;
      if (slot < nv) {
        p0 = fmaxf(p0, acc[mt][0][r]);
        p1 = fmaxf(p1, acc[mt][1][r]);
      }
    }
  }
  p0 = fmaxf(p0, __shfl_xor(p0, 16, 64));
  p0 = fmaxf(p0, __shfl_xor(p0, 32, 64));
  p1 = fmaxf(p1, __shfl_xor(p1, 16, 64));
  p1 = fmaxf(p1, __shfl_xor(p1, 32, 64));
  if (lane < 16) {
    int c = col0 + lane;
    out[(size_t)g*128 + c]      = (nv > 0) ? p0 + b2[c]      : 0.f;
    out[(size_t)g*128 + c + 16] = (nv > 0) ? p1 + b2[c + 16] : 0.f;
  }
}

// ---------------------------------------------------------------- launch
extern "C" void kernel_launch(void* const* d_in, const int* in_sizes, int n_in,
                              void* d_out, int out_size, void* d_ws, size_t ws_size,
                              hipStream_t stream) {
  const float* x   = (const float*)d_in[0];
  const float* pos = (const float*)d_in[1];
  // d_in[2] (batch) unused: layout is known (repeat arange(16), 4096 each)
  const float* W1  = (const float*)d_in[3];
  const float* b1  = (const float*)d_in[4];
  const float* W2  = (const float*)d_in[5];
  const float* b2  = (const float*)d_in[6];

  float* out       = (float*)d_out;                    // [16384,128]
  float* pos_out   = out + (size_t)NB*MPC*128;         // [16384,3]
  float* batch_out = pos_out + (size_t)NB*MPC*3;       // [16384] (written as floats)

  char* ws = (char*)d_ws;
  int* idx    = (int*)(ws);                                    // 16384 * 4   = 64 KB
  int* nvalid = (int*)(ws + 65536);                            // 16384 * 4   = 64 KB
  int* nbr    = (int*)(ws + 131072);                           // 16384*64*4  = 4 MB
  u16* w2t    = (u16*)(ws + 131072 + 4194304);                 // 128*64*2    = 16 KB
  u16* y      = (u16*)(ws + 131072 + 4194304 + 16384);         // 65536*64*2  = 8 MB (16B aligned)

  fps_kernel <<<NB,    512,  0, stream>>>(pos, idx, pos_out, batch_out);
  y_kernel   <<<1024,  256,  0, stream>>>(x, W1, y);
  w2t_kernel <<<32,    256,  0, stream>>>(W2, w2t);
  nbr_kernel <<<4096,  256,  0, stream>>>(pos, idx, nbr, nvalid);
  conv_kernel<<<16384, 256,  0, stream>>>(pos, idx, nbr, nvalid, y, w2t, W1, b1, b2, out);
}